// Round 1
// baseline (507.392 us; speedup 1.0000x reference)
//
#include <hip/hip_runtime.h>

using u16 = unsigned short;
using u32 = unsigned int;
typedef __attribute__((ext_vector_type(8))) __bf16 bf16x8;
typedef __attribute__((ext_vector_type(4))) float f32x4;

#define DEVI __device__ __forceinline__

constexpr int BN_ = 128;              // batch
constexpr int NN  = 1024;             // graph nodes
constexpr int CH  = 66;               // IN_DIM + HID
constexpr int HD  = 64;               // HID
constexpr int RR  = BN_ * CH;         // 8448 rows
constexpr long RN = (long)RR * NN;    // elements per part
constexpr int KTRUE = 330, KPAD = 352;

DEVI float bf2f(u16 u) { u32 i = ((u32)u) << 16; float f; __builtin_memcpy(&f, &i, 4); return f; }
DEVI u16 f2bf(float f) { u32 i; __builtin_memcpy(&i, &f, 4); i += 0x7fffu + ((i >> 16) & 1u); return (u16)(i >> 16); }

DEVI void gl_lds16(const void* g, void* l) {
  __builtin_amdgcn_global_load_lds((const __attribute__((address_space(1))) u32*)g,
                                   (__attribute__((address_space(3))) u32*)l, 16, 0, 0);
}

// ---- GEMM:  Y[r,m] = sum_n X[r,n]*A[m,n]   (CHEB: Y = 2*that - X0) ----
// grid (8, 66, 2): x = n-tile(128), y = m-tile(128 rows of X), z = adjacency
template<bool CHEB>
__global__ __launch_bounds__(256, 2)
void gemm_bt(const u16* __restrict__ Xb, long xz,
             const u16* __restrict__ Ab,
             const u16* __restrict__ X0,
             u16* __restrict__ Yb, long yz)
{
  __shared__ u16 Xs[128 * 32];
  __shared__ u16 Bs[128 * 32];
  const int z = blockIdx.z;
  const u16* X = Xb + (long)z * xz;
  const u16* A = Ab + (long)z * (NN * NN);
  u16*       Y = Yb + (long)z * yz;
  const int tm = blockIdx.y, tn = blockIdx.x;
  const int tid = threadIdx.x, wv = tid >> 6, ln = tid & 63;

  // staging: per wave-inst 1KB = 16 rows x 64B; lane -> row r0, 16B chunk (lane&3)
  // chunk-XOR swizzle on the GLOBAL source (LDS dest stays linear), read applies same XOR
  const int r0  = wv * 16 + (ln >> 2);
  const int kch = (((ln & 3) ^ ((r0 >> 1) & 3))) * 8;
  const u16* gX = X + (long)(tm * 128 + r0) * NN + kch;
  const u16* gA = A + (long)(tn * 128 + r0) * NN + kch;
  u16* lX = &Xs[wv * 512];
  u16* lA = &Bs[wv * 512];

  const int frow = ln & 15;
  const int fk   = ((ln >> 4) ^ ((ln >> 1) & 3)) * 8;  // swizzled k-chunk
  const int wr = wv >> 1, wc = wv & 1;

  f32x4 acc[4][4] = {};

  for (int k0 = 0; k0 < NN; k0 += 32) {
    gl_lds16(gX + k0,            lX);
    gl_lds16(gX + k0 + 64 * NN,  lX + 2048);
    gl_lds16(gA + k0,            lA);
    gl_lds16(gA + k0 + 64 * NN,  lA + 2048);
    __syncthreads();
    bf16x8 af[4], bfv[4];
#pragma unroll
    for (int m = 0; m < 4; m++) af[m]  = *(const bf16x8*)&Xs[(wr * 64 + m * 16 + frow) * 32 + fk];
#pragma unroll
    for (int n = 0; n < 4; n++) bfv[n] = *(const bf16x8*)&Bs[(wc * 64 + n * 16 + frow) * 32 + fk];
#pragma unroll
    for (int m = 0; m < 4; m++)
#pragma unroll
      for (int n = 0; n < 4; n++)
        acc[m][n] = __builtin_amdgcn_mfma_f32_16x16x32_bf16(af[m], bfv[n], acc[m][n], 0, 0, 0);
    __syncthreads();
  }

  // C/D layout: col = lane&15, row = (lane>>4)*4 + q   [m89-verified]
  const int colb = tn * 128 + wc * 64 + frow;
  const int rowb = tm * 128 + wr * 64 + (ln >> 4) * 4;
#pragma unroll
  for (int m = 0; m < 4; m++)
#pragma unroll
    for (int n = 0; n < 4; n++) {
      const int col = colb + n * 16;
#pragma unroll
      for (int q = 0; q < 4; q++) {
        const long r = rowb + m * 16 + q;
        float v = acc[m][n][q];
        if (CHEB) v = 2.0f * v - bf2f(X0[r * NN + col]);
        Y[r * NN + col] = f2bf(v);
      }
    }
}

// ---- projection: out[b,o,n] = act( sum_c W[o,c]*h[b,c,n] + bias[o] ) ----
// h parts: part0 (X or XC) + 4 contiguous Y parts. K padded 330->352 (zeros).
// grid (16, B): x = n-tile(64), y = b.  LDS holds h-tile TRANSPOSED: Ts[n][c], pad 360.
template<int O, bool FINAL>
__global__ __launch_bounds__(256, 2)
void proj_act(const u16* __restrict__ part0, const u16* __restrict__ ybase,
              const u16* __restrict__ W, const float* __restrict__ bias,
              const float* __restrict__ hx, u16* __restrict__ xc,
              float* __restrict__ ubuf, float* __restrict__ outp)
{
  __shared__ u16 Ts[64 * 360];
  const int b = blockIdx.y, tnb = blockIdx.x;
  const int tid = threadIdx.x;
  const int nc0 = tnb * 64;

  // stage transposed: 352*32 4B-chunks / 256 threads = 44 iters exactly
  for (int it = 0; it < 44; ++it) {
    const int idx = it * 256 + tid;
    const int c = idx >> 5;
    const int n = (idx & 31) * 2;
    u32 v = 0;
    if (c < KTRUE) {
      const u32 p = (u32)c / 66u;
      const u32 f = (u32)c - p * 66u;
      const u16* src = p ? (ybase + (long)(p - 1) * RN) : part0;
      v = *(const u32*)&src[(long)(b * CH + f) * NN + nc0 + n];
    }
    Ts[n * 360 + c]       = (u16)(v & 0xffffu);
    Ts[(n + 1) * 360 + c] = (u16)(v >> 16);
  }
  __syncthreads();

  const int wv = tid >> 6, ln = tid & 63;
  const int wo = wv >> 1, wn = wv & 1;
  constexpr int FO = O / 32;
  const int frow = ln & 15, fkb = (ln >> 4) * 8;
  f32x4 acc[FO][2] = {};

  for (int k0 = 0; k0 < KPAD; k0 += 32) {
    bf16x8 bt0 = *(const bf16x8*)&Ts[(wn * 32 +      frow) * 360 + k0 + fkb];
    bf16x8 bt1 = *(const bf16x8*)&Ts[(wn * 32 + 16 + frow) * 360 + k0 + fkb];
#pragma unroll
    for (int m = 0; m < FO; m++) {
      bf16x8 aw = *(const bf16x8*)&W[(long)(wo * (O / 2) + m * 16 + frow) * KPAD + k0 + fkb];
      acc[m][0] = __builtin_amdgcn_mfma_f32_16x16x32_bf16(aw, bt0, acc[m][0], 0, 0, 0);
      acc[m][1] = __builtin_amdgcn_mfma_f32_16x16x32_bf16(aw, bt1, acc[m][1], 0, 0, 0);
    }
  }

#pragma unroll
  for (int m = 0; m < FO; m++)
#pragma unroll
    for (int n2 = 0; n2 < 2; n2++) {
      const int ob   = wo * (O / 2) + m * 16 + (ln >> 4) * 4;
      const int ncol = nc0 + wn * 32 + n2 * 16 + frow;
#pragma unroll
      for (int q = 0; q < 4; q++) {
        const int o = ob + q;
        const float pre = acc[m][n2][q] + bias[o];
        if (!FINAL) {
          const float s = 1.0f / (1.0f + __expf(-pre));
          if (o < HD) {  // r -> write bf16(r*hx) into XC channel 2+o
            const float hv = hx[(long)(b * HD + o) * NN + ncol];
            xc[(long)(b * CH + 2 + o) * NN + ncol] = f2bf(s * hv);
          } else {       // u -> f32 buffer
            ubuf[(long)(b * HD + (o - HD)) * NN + ncol] = s;
          }
        } else {
          const float e  = __expf(2.0f * pre);
          const float cc = 1.0f - 2.0f / (e + 1.0f);    // tanh(pre)
          const long oi = (long)(b * HD + o) * NN + ncol;
          const float u = ubuf[oi];
          outp[oi] = u * hx[oi] + (1.0f - u) * cc;
        }
      }
    }
}

// ---- build X = bf16([inputs; hx]) rows; also seed XC's input channels ----
__global__ void build_x(const float* __restrict__ inp, const float* __restrict__ hx,
                        u16* __restrict__ X, u16* __restrict__ XC)
{
  const int row = blockIdx.x;           // 0..8447
  const int b = row / 66, f = row - b * 66;
  const int n0 = threadIdx.x * 4;
  const float* s = (f < 2) ? (inp + (long)(b * 2 + f) * NN) : (hx + (long)(b * HD + f - 2) * NN);
  const float4 v = *(const float4*)(s + n0);
  ushort4 o;
  o.x = f2bf(v.x); o.y = f2bf(v.y); o.z = f2bf(v.z); o.w = f2bf(v.w);
  *(ushort4*)&X[(long)row * NN + n0] = o;
  if (f < 2) *(ushort4*)&XC[(long)row * NN + n0] = o;
}

// ---- convert A0,A1 -> bf16; pad+convert W_ru,W_C to [O][352] bf16 ----
__global__ void prep(const float* __restrict__ A0, const float* __restrict__ A1,
                     const float* __restrict__ Wru, const float* __restrict__ WC,
                     u16* __restrict__ Abf, u16* __restrict__ Wrub, u16* __restrict__ WCb)
{
  const int gid = blockIdx.x * 256 + threadIdx.x;
  if (gid < 524288) {                    // 2*1024*1024 / 4
    const float* s = (gid < 262144) ? (A0 + (long)gid * 4) : (A1 + (long)(gid - 262144) * 4);
    const float4 v = *(const float4*)s;
    ushort4 o; o.x = f2bf(v.x); o.y = f2bf(v.y); o.z = f2bf(v.z); o.w = f2bf(v.w);
    *(ushort4*)&Abf[(long)gid * 4] = o;
  } else if (gid < 524288 + 128 * KPAD) {
    const int g = gid - 524288;
    const int o = g / KPAD, c = g - o * KPAD;
    Wrub[g] = f2bf(c < KTRUE ? Wru[o * KTRUE + c] : 0.0f);
  } else if (gid < 524288 + 128 * KPAD + 64 * KPAD) {
    const int g = gid - 524288 - 128 * KPAD;
    const int o = g / KPAD, c = g - o * KPAD;
    WCb[g] = f2bf(c < KTRUE ? WC[o * KTRUE + c] : 0.0f);
  }
}

extern "C" void kernel_launch(void* const* d_in, const int* in_sizes, int n_in,
                              void* d_out, int out_size, void* d_ws, size_t ws_size,
                              hipStream_t stream)
{
  const float* inp = (const float*)d_in[0];
  const float* hx  = (const float*)d_in[1];
  const float* A0  = (const float*)d_in[2];
  const float* A1  = (const float*)d_in[3];
  const float* Wru = (const float*)d_in[4];
  const float* bru = (const float*)d_in[5];
  const float* WC  = (const float*)d_in[6];
  const float* bC  = (const float*)d_in[7];
  float* out = (float*)d_out;

  char* ws = (char*)d_ws;
  u16* Abf   = (u16*)(ws);               //  4,194,304 B  (2 x 1024x1024 bf16)
  u16* Wrub  = (u16*)(ws + 4194304);     //     90,112 B  (128x352)
  u16* WCb   = (u16*)(ws + 4284416);     //     45,056 B  (64x352)
  u16* X     = (u16*)(ws + 4329472);     // 17,301,504 B  (8448x1024 bf16)
  u16* XC    = (u16*)(ws + 21630976);    // 17,301,504 B
  u16* Yb    = (u16*)(ws + 38932480);    // 69,206,016 B  (4 parts)
  float* ub  = (float*)(ws + 108138496); // 33,554,432 B  -> total 141,692,928 B

  prep<<<2312, 256, 0, stream>>>(A0, A1, Wru, WC, Abf, Wrub, WCb);
  build_x<<<RR, 256, 0, stream>>>(inp, hx, X, XC);

  const dim3 gg(8, 66, 2);
  // phase 1: h = [X, Y1_0, Y2_0, Y1_1, Y2_1]
  gemm_bt<false><<<gg, 256, 0, stream>>>(X, 0, Abf, nullptr, Yb, 2 * RN);
  gemm_bt<true ><<<gg, 256, 0, stream>>>(Yb, 2 * RN, Abf, X, Yb + RN, 2 * RN);
  proj_act<128, false><<<dim3(16, BN_), 256, 0, stream>>>(X, Yb, Wrub, bru, hx, XC, ub, nullptr);
  // phase 2: hc = [XC, ...] (Y buffers reused)
  gemm_bt<false><<<gg, 256, 0, stream>>>(XC, 0, Abf, nullptr, Yb, 2 * RN);
  gemm_bt<true ><<<gg, 256, 0, stream>>>(Yb, 2 * RN, Abf, XC, Yb + RN, 2 * RN);
  proj_act<64, true ><<<dim3(16, BN_), 256, 0, stream>>>(XC, Yb, WCb, bC, hx, XC, ub, out);
}